// Round 8
// baseline (260.199 us; speedup 1.0000x reference)
//
#include <hip/hip_runtime.h>
#include <math.h>

// Problem constants
#define NPROJ 4112          // P = 2*H*K + H*V + 2*H + UNITS
#define HOFF  0                                  // h_t  : 512*1024
#define COFF  524288                             // C_t  : 512*8*128*128
#define NOFF  67633152                           // n_t  : 512*1024
#define SLICE 2105344                            // 512*4112 (one split-K partial)

// ---------------------------------------------------------------------------
// Kernel 1: split-K fp32 GEMM over ALL 4112 cols (guarded 65th col tile).
//   z=0: X0,W0 k[0,512)   z=1: X0,W0 k[512,1024)
//   z=2: X1,W1 k[0,512)   z=3: X1,W1 k[512,1024)
// BM=64, BN=64, BK=64, 256 threads, 4x4/thread. fp32 FMA, 32-term chunks
// flushed to fp64 (proven cadence: absmax 32). Grid (65,8,4)=2080 blocks,
// 4 blocks/CU resident (34KB LDS, ~80 VGPR) -> 2 balanced rounds.
// BK=64: 16 barriers/block (was 32), 8 staging loads in flight (was 4).
// ---------------------------------------------------------------------------
__global__ __launch_bounds__(256)
void proj_gemm_sk(const float* __restrict__ X0, const float* __restrict__ X1,
                  const float* __restrict__ W0, const float* __restrict__ W1,
                  float* __restrict__ pbuf)
{
    const int K = 1024;
    const int N = NPROJ;
    __shared__ float As[64][68];   // [k][row]
    __shared__ float Bs[64][68];   // [k][col]

    const int tid  = threadIdx.x;
    const int row0 = blockIdx.y * 64;
    const int col0 = blockIdx.x * 64;          // 0..4096 (last tile has 16 cols)
    const int z    = blockIdx.z;
    const float* __restrict__ A = (z < 2) ? X0 : X1;
    const float* __restrict__ W = (z < 2) ? W0 : W1;
    const int kbase = (z & 1) << 9;            // 0 or 512
    const int tx = tid & 15, ty = tid >> 4;

    // staging assignment
    const int ar = tid >> 2;                   // A row 0..63
    const int aq = (tid & 3) << 2;             // A k-quad {0,4,8,12} (+16/32/48)
    const int bk = tid >> 4;                   // B k-row 0..15 (+16/32/48)
    const int bn = (tid & 15) << 2;            // B col 0..60
    const int gn = col0 + bn;
    const bool bok = gn < N;

    float  acc32[4][4];
    double acc64[4][4];
#pragma unroll
    for (int i = 0; i < 4; ++i)
#pragma unroll
        for (int j = 0; j < 4; ++j) { acc32[i][j] = 0.f; acc64[i][j] = 0.0; }

    for (int kt = 0; kt < 8; ++kt) {
        const int k0 = kbase + (kt << 6);
        // stage A: 64 rows x 64 k (4 float4 per thread, issued back-to-back)
        {
            const float* __restrict__ arow = A + (size_t)(row0 + ar) * K + k0 + aq;
            const float4 a0 = *(const float4*)(arow);
            const float4 a1 = *(const float4*)(arow + 16);
            const float4 a2 = *(const float4*)(arow + 32);
            const float4 a3 = *(const float4*)(arow + 48);
            As[aq + 0][ar] = a0.x; As[aq + 1][ar] = a0.y;
            As[aq + 2][ar] = a0.z; As[aq + 3][ar] = a0.w;
            As[aq + 16][ar] = a1.x; As[aq + 17][ar] = a1.y;
            As[aq + 18][ar] = a1.z; As[aq + 19][ar] = a1.w;
            As[aq + 32][ar] = a2.x; As[aq + 33][ar] = a2.y;
            As[aq + 34][ar] = a2.z; As[aq + 35][ar] = a2.w;
            As[aq + 48][ar] = a3.x; As[aq + 49][ar] = a3.y;
            As[aq + 50][ar] = a3.z; As[aq + 51][ar] = a3.w;
        }
        // stage B: 64 k x 64 n (4 float4 per thread, guarded zero-fill)
        {
            float4 b0 = make_float4(0.f, 0.f, 0.f, 0.f), b1 = b0, b2 = b0, b3 = b0;
            if (bok) {
                b0 = *(const float4*)(W + (size_t)(k0 + bk) * N + gn);
                b1 = *(const float4*)(W + (size_t)(k0 + bk + 16) * N + gn);
                b2 = *(const float4*)(W + (size_t)(k0 + bk + 32) * N + gn);
                b3 = *(const float4*)(W + (size_t)(k0 + bk + 48) * N + gn);
            }
            *(float4*)&Bs[bk][bn]      = b0;
            *(float4*)&Bs[bk + 16][bn] = b1;
            *(float4*)&Bs[bk + 32][bn] = b2;
            *(float4*)&Bs[bk + 48][bn] = b3;
        }
        __syncthreads();
        // first 32 k-terms
#pragma unroll
        for (int kk = 0; kk < 32; ++kk) {
            const float4 av = *(const float4*)&As[kk][ty << 2];
            const float4 bv = *(const float4*)&Bs[kk][tx << 2];
            const float aa[4] = {av.x, av.y, av.z, av.w};
            const float bb[4] = {bv.x, bv.y, bv.z, bv.w};
#pragma unroll
            for (int i = 0; i < 4; ++i)
#pragma unroll
                for (int j = 0; j < 4; ++j)
                    acc32[i][j] = fmaf(aa[i], bb[j], acc32[i][j]);
        }
#pragma unroll
        for (int i = 0; i < 4; ++i)
#pragma unroll
            for (int j = 0; j < 4; ++j) {
                acc64[i][j] += (double)acc32[i][j];
                acc32[i][j] = 0.f;
            }
        // second 32 k-terms
#pragma unroll
        for (int kk = 32; kk < 64; ++kk) {
            const float4 av = *(const float4*)&As[kk][ty << 2];
            const float4 bv = *(const float4*)&Bs[kk][tx << 2];
            const float aa[4] = {av.x, av.y, av.z, av.w};
            const float bb[4] = {bv.x, bv.y, bv.z, bv.w};
#pragma unroll
            for (int i = 0; i < 4; ++i)
#pragma unroll
                for (int j = 0; j < 4; ++j)
                    acc32[i][j] = fmaf(aa[i], bb[j], acc32[i][j]);
        }
#pragma unroll
        for (int i = 0; i < 4; ++i)
#pragma unroll
            for (int j = 0; j < 4; ++j) {
                acc64[i][j] += (double)acc32[i][j];
                acc32[i][j] = 0.f;
            }
        __syncthreads();
    }

    // store fp32 partial to pbuf[z] (dense [512][4112] per slice, guarded)
    float* __restrict__ dst = pbuf + (size_t)z * SLICE;
    const int c = col0 + (tx << 2);
    if (c < N) {
#pragma unroll
        for (int i = 0; i < 4; ++i) {
            const int row = row0 + (ty << 2) + i;
            float4 w;
            w.x = (float)acc64[i][0];
            w.y = (float)acc64[i][1];
            w.z = (float)acc64[i][2];
            w.w = (float)acc64[i][3];
            *(float4*)(dst + (size_t)row * N + c) = w;
        }
    }
}

// ---------------------------------------------------------------------------
// fp64 sum of the 4 split-K partials + bias (the fused "reduce").
// ---------------------------------------------------------------------------
__device__ __forceinline__ double psum4(const float* __restrict__ pb, size_t off, float bv)
{
    return (((double)pb[off] + (double)pb[off + SLICE]) +
            ((double)pb[off + 2 * (size_t)SLICE] + (double)pb[off + 3 * (size_t)SLICE])) +
           (double)bv;
}

// ---------------------------------------------------------------------------
// Kernel 2 (main path): fused mLSTM update reading split-K partials directly.
// One block per (b,h). fp64 internals; HBM-bound (~540MB C stream + 34MB proj
// partial reads). Saves the separate reduce kernel + one proj rounding.
// ---------------------------------------------------------------------------
__global__ __launch_bounds__(256)
void mlstm_update_fused(const float* __restrict__ pbuf, const float* __restrict__ bias,
                        const float* __restrict__ C_tm1, const float* __restrict__ n_tm1,
                        float* __restrict__ out)
{
    const int bh = blockIdx.x;
    const int b  = bh >> 3;
    const int h  = bh & 7;
    const int t  = threadIdx.x;
    const size_t pb = (size_t)b * NPROJ;

    __shared__ double q_s[128];
    __shared__ double coef_s[128];
    __shared__ double prod_s[128];
    __shared__ double red_s[8][128];
    __shared__ double denom_s;

    const double ig = exp(psum4(pbuf, pb + 3072 + h, bias[3072 + h]));
    const double fg = 1.0 / (1.0 + exp(-psum4(pbuf, pb + 3080 + h, bias[3080 + h])));

    if (t < 128) {
        const double qv = psum4(pbuf, pb + h * 128 + t, bias[h * 128 + t]);
        const double kv = psum4(pbuf, pb + 1024 + h * 128 + t, bias[1024 + h * 128 + t]);
        q_s[t]    = qv;
        const double cf = ig * kv;
        coef_s[t] = cf;
        const double nv = fma(fg, (double)n_tm1[(size_t)b * 1024 + h * 128 + t], cf);
        out[NOFF + (size_t)b * 1024 + h * 128 + t] = (float)nv;
        prod_s[t] = nv * qv;
    }
    __syncthreads();

    const int g = t >> 5;
    const int s = t & 31;
    const float4* __restrict__ Cin  = (const float4*)(C_tm1 + (size_t)bh * 16384);
    float4*       __restrict__ Cout = (float4*)(out + COFF + (size_t)bh * 16384);
    double v0, v1, v2, v3;
    {
        const size_t vo = pb + 2048 + h * 128 + (s << 2);
        v0 = psum4(pbuf, vo + 0, bias[2048 + h * 128 + (s << 2) + 0]);
        v1 = psum4(pbuf, vo + 1, bias[2048 + h * 128 + (s << 2) + 1]);
        v2 = psum4(pbuf, vo + 2, bias[2048 + h * 128 + (s << 2) + 2]);
        v3 = psum4(pbuf, vo + 3, bias[2048 + h * 128 + (s << 2) + 3]);
    }

    double r0 = 0.0, r1 = 0.0, r2 = 0.0, r3 = 0.0;
#pragma unroll 4
    for (int it = 0; it < 16; ++it) {
        const int kr = (it << 3) + g;
        const float4 cc = Cin[(kr << 5) + s];
        const double cf = coef_s[kr];
        const double qv = q_s[kr];
        const double c0 = fma(fg, (double)cc.x, cf * v0);
        const double c1 = fma(fg, (double)cc.y, cf * v1);
        const double c2 = fma(fg, (double)cc.z, cf * v2);
        const double c3 = fma(fg, (double)cc.w, cf * v3);
        float4 cn;
        cn.x = (float)c0; cn.y = (float)c1; cn.z = (float)c2; cn.w = (float)c3;
        Cout[(kr << 5) + s] = cn;
        r0 = fma(c0, qv, r0);
        r1 = fma(c1, qv, r1);
        r2 = fma(c2, qv, r2);
        r3 = fma(c3, qv, r3);
    }
    red_s[g][(s << 2) + 0] = r0;
    red_s[g][(s << 2) + 1] = r1;
    red_s[g][(s << 2) + 2] = r2;
    red_s[g][(s << 2) + 3] = r3;
    __syncthreads();

    if (t < 64) {
        double x = prod_s[t] + prod_s[t + 64];
#pragma unroll
        for (int off = 32; off > 0; off >>= 1) x += __shfl_xor(x, off, 64);
        if (t == 0) denom_s = x + 1e-8;
    }
    __syncthreads();

    if (t < 32) {
        double r[4] = {0.0, 0.0, 0.0, 0.0};
#pragma unroll
        for (int gg = 0; gg < 8; ++gg) {
#pragma unroll
            for (int j = 0; j < 4; ++j) r[j] += red_s[gg][(t << 2) + j];
        }
        const double inv = 1.0 / denom_s;
        const size_t oo = pb + 3088 + h * 128 + (t << 2);
        const int    ob = 3088 + h * 128 + (t << 2);
        float4 hv;
        hv.x = (float)((1.0 / (1.0 + exp(-psum4(pbuf, oo + 0, bias[ob + 0])))) * (r[0] * inv));
        hv.y = (float)((1.0 / (1.0 + exp(-psum4(pbuf, oo + 1, bias[ob + 1])))) * (r[1] * inv));
        hv.z = (float)((1.0 / (1.0 + exp(-psum4(pbuf, oo + 2, bias[ob + 2])))) * (r[2] * inv));
        hv.w = (float)((1.0 / (1.0 + exp(-psum4(pbuf, oo + 3, bias[ob + 3])))) * (r[3] * inv));
        *(float4*)(out + HOFF + (size_t)b * 1024 + h * 128 + (t << 2)) = hv;
    }
}

// ---------------------------------------------------------------------------
// Fallback fp32 GEMM (proven R3: 240us, absmax 64) — used if ws too small.
// ---------------------------------------------------------------------------
__global__ __launch_bounds__(256)
void proj_gemm_fp32(const float* __restrict__ X0, const float* __restrict__ X1,
                    const float* __restrict__ W0, const float* __restrict__ W1,
                    const float* __restrict__ bias, float* __restrict__ proj)
{
    const int N = NPROJ;
    const int K = 1024;
    __shared__ float As[16][68];
    __shared__ float Bs[16][68];
    const int tid  = threadIdx.x;
    const int row0 = blockIdx.y * 64;
    const int col0 = blockIdx.x * 64;
    const int tx   = tid & 15;
    const int ty   = tid >> 4;
    float  acc32[4][4];
    double acc64[4][4];
#pragma unroll
    for (int i = 0; i < 4; ++i)
#pragma unroll
        for (int j = 0; j < 4; ++j) { acc32[i][j] = 0.f; acc64[i][j] = 0.0; }
    for (int src = 0; src < 2; ++src) {
        const float* __restrict__ A = src ? X1 : X0;
        const float* __restrict__ W = src ? W1 : W0;
        for (int kt = 0; kt < 64; ++kt) {
            const int k0 = kt << 4;
            {
                const int r  = tid >> 2;
                const int kq = (tid & 3) << 2;
                const float4 a = *(const float4*)(A + (size_t)(row0 + r) * K + k0 + kq);
                As[kq + 0][r] = a.x; As[kq + 1][r] = a.y;
                As[kq + 2][r] = a.z; As[kq + 3][r] = a.w;
            }
            {
                const int kr = tid >> 4;
                const int nc = (tid & 15) << 2;
                const int gn = col0 + nc;
                float4 bv = make_float4(0.f, 0.f, 0.f, 0.f);
                if (gn < N) bv = *(const float4*)(W + (size_t)(k0 + kr) * N + gn);
                *(float4*)&Bs[kr][nc] = bv;
            }
            __syncthreads();
#pragma unroll
            for (int kk = 0; kk < 16; ++kk) {
                const float4 av = *(const float4*)&As[kk][ty << 2];
                const float4 bv = *(const float4*)&Bs[kk][tx << 2];
                const float aa[4] = {av.x, av.y, av.z, av.w};
                const float bb[4] = {bv.x, bv.y, bv.z, bv.w};
#pragma unroll
                for (int i = 0; i < 4; ++i)
#pragma unroll
                    for (int j = 0; j < 4; ++j)
                        acc32[i][j] = fmaf(aa[i], bb[j], acc32[i][j]);
            }
            __syncthreads();
            if (kt & 1) {
#pragma unroll
                for (int i = 0; i < 4; ++i)
#pragma unroll
                    for (int j = 0; j < 4; ++j) {
                        acc64[i][j] += (double)acc32[i][j];
                        acc32[i][j] = 0.f;
                    }
            }
        }
    }
    const int c = col0 + (tx << 2);
    if (c < N) {
#pragma unroll
        for (int i = 0; i < 4; ++i) {
            const int row = row0 + (ty << 2) + i;
            float4 w;
            w.x = (float)(acc64[i][0] + (double)bias[c + 0]);
            w.y = (float)(acc64[i][1] + (double)bias[c + 1]);
            w.z = (float)(acc64[i][2] + (double)bias[c + 2]);
            w.w = (float)(acc64[i][3] + (double)bias[c + 3]);
            *(float4*)(proj + (size_t)row * N + c) = w;
        }
    }
}

// ---------------------------------------------------------------------------
// Fallback update (reads rounded fp32 proj) — R2-proven.
// ---------------------------------------------------------------------------
__global__ __launch_bounds__(256)
void mlstm_update(const float* __restrict__ proj, const float* __restrict__ C_tm1,
                  const float* __restrict__ n_tm1, float* __restrict__ out)
{
    const int bh = blockIdx.x;
    const int b  = bh >> 3;
    const int h  = bh & 7;
    const int t  = threadIdx.x;
    const float* __restrict__ pr = proj + (size_t)b * NPROJ;

    __shared__ double q_s[128];
    __shared__ double coef_s[128];
    __shared__ double prod_s[128];
    __shared__ double red_s[8][128];
    __shared__ double denom_s;

    const double ig = exp((double)pr[3072 + h]);
    const double fg = 1.0 / (1.0 + exp(-(double)pr[3080 + h]));

    if (t < 128) {
        const double qv = (double)pr[h * 128 + t];
        const double kv = (double)pr[1024 + h * 128 + t];
        q_s[t]    = qv;
        const double cf = ig * kv;
        coef_s[t] = cf;
        const double nv = fma(fg, (double)n_tm1[(size_t)b * 1024 + h * 128 + t], cf);
        out[NOFF + (size_t)b * 1024 + h * 128 + t] = (float)nv;
        prod_s[t] = nv * qv;
    }
    __syncthreads();

    const int g = t >> 5;
    const int s = t & 31;
    const float4* __restrict__ Cin  = (const float4*)(C_tm1 + (size_t)bh * 16384);
    float4*       __restrict__ Cout = (float4*)(out + COFF + (size_t)bh * 16384);
    const float4 vf = *(const float4*)(pr + 2048 + h * 128 + (s << 2));
    const double v0 = (double)vf.x, v1 = (double)vf.y, v2 = (double)vf.z, v3 = (double)vf.w;

    double r0 = 0.0, r1 = 0.0, r2 = 0.0, r3 = 0.0;
#pragma unroll 4
    for (int it = 0; it < 16; ++it) {
        const int kr = (it << 3) + g;
        const float4 cc = Cin[(kr << 5) + s];
        const double cf = coef_s[kr];
        const double qv = q_s[kr];
        const double c0 = fma(fg, (double)cc.x, cf * v0);
        const double c1 = fma(fg, (double)cc.y, cf * v1);
        const double c2 = fma(fg, (double)cc.z, cf * v2);
        const double c3 = fma(fg, (double)cc.w, cf * v3);
        float4 cn;
        cn.x = (float)c0; cn.y = (float)c1; cn.z = (float)c2; cn.w = (float)c3;
        Cout[(kr << 5) + s] = cn;
        r0 = fma(c0, qv, r0);
        r1 = fma(c1, qv, r1);
        r2 = fma(c2, qv, r2);
        r3 = fma(c3, qv, r3);
    }
    red_s[g][(s << 2) + 0] = r0;
    red_s[g][(s << 2) + 1] = r1;
    red_s[g][(s << 2) + 2] = r2;
    red_s[g][(s << 2) + 3] = r3;
    __syncthreads();

    if (t < 64) {
        double x = prod_s[t] + prod_s[t + 64];
#pragma unroll
        for (int off = 32; off > 0; off >>= 1) x += __shfl_xor(x, off, 64);
        if (t == 0) denom_s = x + 1e-8;
    }
    __syncthreads();

    if (t < 32) {
        double r[4] = {0.0, 0.0, 0.0, 0.0};
#pragma unroll
        for (int gg = 0; gg < 8; ++gg) {
#pragma unroll
            for (int j = 0; j < 4; ++j) r[j] += red_s[gg][(t << 2) + j];
        }
        const double inv = 1.0 / denom_s;
        const float* oo = pr + 3088 + h * 128 + (t << 2);
        float4 hv;
        hv.x = (float)((1.0 / (1.0 + exp(-(double)oo[0]))) * (r[0] * inv));
        hv.y = (float)((1.0 / (1.0 + exp(-(double)oo[1]))) * (r[1] * inv));
        hv.z = (float)((1.0 / (1.0 + exp(-(double)oo[2]))) * (r[2] * inv));
        hv.w = (float)((1.0 / (1.0 + exp(-(double)oo[3]))) * (r[3] * inv));
        *(float4*)(out + HOFF + (size_t)b * 1024 + h * 128 + (t << 2)) = hv;
    }
}

// ---------------------------------------------------------------------------
extern "C" void kernel_launch(void* const* d_in, const int* in_sizes, int n_in,
                              void* d_out, int out_size, void* d_ws, size_t ws_size,
                              hipStream_t stream)
{
    const float* inputs  = (const float*)d_in[0];   // (512, 1024)
    const float* h_tm1   = (const float*)d_in[1];   // (512, 1024)
    const float* C_tm1   = (const float*)d_in[2];   // (512, 8*128*128)
    const float* n_tm1   = (const float*)d_in[3];   // (512, 8*128)
    const float* kernelW = (const float*)d_in[4];   // (1024, 4112)
    const float* rkernel = (const float*)d_in[5];   // (1024, 4112)
    const float* bias    = (const float*)d_in[6];   // (4112,)
    float* out  = (float*)d_out;
    float* proj = (float*)d_ws;                     // fallback proj buffer

    const size_t SZ_PROJ = (size_t)SLICE * 4;                  // 8,421,376
    const size_t SZ_PART = (size_t)4 * SLICE * 4;              // 33,685,504
    const size_t NEED    = SZ_PROJ + SZ_PART;                  // ~42.1 MB

    if (ws_size >= NEED) {
        float* pbuf = (float*)((char*)d_ws + SZ_PROJ);
        proj_gemm_sk<<<dim3(65, 8, 4), dim3(256), 0, stream>>>(inputs, h_tm1, kernelW, rkernel, pbuf);
        mlstm_update_fused<<<dim3(4096), dim3(256), 0, stream>>>(pbuf, bias, C_tm1, n_tm1, out);
    } else {
        proj_gemm_fp32<<<dim3(65, 8), dim3(256), 0, stream>>>(inputs, h_tm1, kernelW, rkernel, bias, proj);
        mlstm_update<<<dim3(4096), dim3(256), 0, stream>>>(proj, C_tm1, n_tm1, out);
    }
}